// Round 1
// baseline (134.091 us; speedup 1.0000x reference)
//
#include <hip/hip_runtime.h>
#include <hip/hip_bf16.h>
#include <math.h>

// Problem constants (fixed by reference)
#define NFRAMES 32
#define NPED    128
#define HDIM    64
#define GRIDG   8
#define KDIM    4096     // G*G*H
#define OUTD    64
#define EPSV    1e-5f
#define CHUNK   16       // pedestrians per block in fused kernel
#define NBLK    256      // NFRAMES * (NPED/CHUNK)
#define PROW    4104     // 4096 + 8 bf16 pad: row stride 8208 B -> bank shift 4/row, 16B aligned

typedef __attribute__((ext_vector_type(8))) short  short8;
typedef __attribute__((ext_vector_type(4))) float  floatx4;

static __device__ __forceinline__ unsigned short f2bf(float f) {
    union { float f; unsigned u; } v; v.f = f;
    unsigned r = v.u + 0x7fffu + ((v.u >> 16) & 1u);   // RNE (no NaNs in this data)
    return (unsigned short)(r >> 16);
}
static __device__ __forceinline__ float bf2f(unsigned short s) {
    union { unsigned u; float f; } v; v.u = ((unsigned)s) << 16;
    return v.f;
}

// Kernel 0: Wt[o][k] = bf16(W[k][o])  (so MFMA B-fragments are contiguous 16B loads)
__global__ void k_wt(const float* __restrict__ W, unsigned short* __restrict__ Wt) {
    int g = blockIdx.x * 256 + threadIdx.x;   // g = o*KDIM + k
    int o = g >> 12;
    int k = g & (KDIM - 1);
    Wt[g] = f2bf(W[k * OUTD + o]);
}

// Kernel 1: fused social-pool (bf16 LDS scatter) + MFMA GEMM + BN partial sums.
// One block per (frame, 16-ped chunk): 256 blocks, 256 threads (4 waves).
__global__ __launch_bounds__(256, 1) void k_fused(
    const float* __restrict__ hs, const float* __restrict__ pos,
    const unsigned short* __restrict__ Wt,
    float* __restrict__ x, float* __restrict__ psum, float* __restrict__ psumsq)
{
    __shared__ unsigned short P[CHUNK * PROW];   // 131328 B pooled bf16, row-padded
    __shared__ float posL[NPED * 2];             // frame positions

    const int tid   = threadIdx.x;
    const int bid   = blockIdx.x;
    const int f     = bid >> 3;                  // frame
    const int chunk = bid & 7;                   // 16-ped chunk within frame
    const int lane  = tid & 63;
    const int w     = tid >> 6;                  // wave id 0..3

    // stage positions for this frame (exactly 256 floats)
    posL[tid] = pos[f * (NPED * 2) + tid];
    // zero pooled buffer (incl. pad)
    unsigned* P32 = (unsigned*)P;
    for (int idx = tid; idx < CHUNK * PROW / 2; idx += 256) P32[idx] = 0u;
    __syncthreads();

    // ---- Phase 1: pooling. wave w owns i_local = w*4 + r (r=0..3); lane = h. ----
    {
        float xi[4], yi[4];
        int   ifr[4];
        #pragma unroll
        for (int r = 0; r < 4; ++r) {
            int il = w * 4 + r;
            ifr[r] = chunk * CHUNK + il;         // within-frame pedestrian index
            xi[r] = posL[ifr[r] * 2];
            yi[r] = posL[ifr[r] * 2 + 1];
        }
        const float* hsF = hs + f * (NPED * HDIM);
        for (int j = 0; j < NPED; ++j) {
            float xj = posL[j * 2];
            float yj = posL[j * 2 + 1];
            float hv = hsF[j * HDIM + lane];     // coalesced, L1-hot (32 KB/frame)
            #pragma unroll
            for (int r = 0; r < 4; ++r) {
                float tlx = xi[r] - 1.0f, tly = yi[r] + 1.0f;
                float brx = xi[r] + 1.0f, bry = yi[r] - 1.0f;
                bool bad = (xj <= tlx) | (yj >= tly) | (xj >= brx) | (yj <= bry) | (j == ifr[r]);
                if (!bad) {                       // wave-uniform branch
                    int gx = (int)floorf((xj - tlx) * 4.0f);  // == floor(((xj-tlx)/NS)*G) exactly
                    int gy = (int)floorf((tly - yj) * 4.0f);
                    int c  = gx + GRIDG * gy;
                    int a  = (w * 4 + r) * PROW + c * HDIM + lane;
                    P[a] = f2bf(bf2f(P[a]) + hv); // bf16 RMW accumulate
                }
            }
        }
    }
    __syncthreads();

    // ---- Phase 2: X[16 i][64 o] = P[16,4096] @ Wt^T; wave w -> o-tile [w*16, w*16+16) ----
    const int m    = lane & 15;                  // A row (i_local) / D col
    const int quad = lane >> 4;
    floatx4 acc[4];
    #pragma unroll
    for (int u = 0; u < 4; ++u) acc[u] = (floatx4){0.f, 0.f, 0.f, 0.f};

    const unsigned short* wtBase = Wt + (size_t)(w * 16 + m) * KDIM;  // B: n = lane&15
    const unsigned short* pBase  = P + m * PROW;

    for (int kk = 0; kk < KDIM; kk += 128) {
        #pragma unroll
        for (int u = 0; u < 4; ++u) {
            int k0 = kk + u * 32 + quad * 8;     // k = quad*8 + elem  (A and B identical mapping)
            short8 afrag = *(const short8*)(pBase + k0);    // ds_read_b128, 2-way bank alias (free)
            short8 bfrag = *(const short8*)(wtBase + k0);   // global dwordx4, contiguous 16B
            acc[u] = __builtin_amdgcn_mfma_f32_16x16x32_bf16(afrag, bfrag, acc[u], 0, 0, 0);
        }
    }
    floatx4 accf = acc[0] + acc[1];
    accf = accf + acc[2];
    accf = accf + acc[3];

    // ---- Epilogue: write x, per-block BN partials (bias b cancels through BN) ----
    const int ibase = f * NPED + chunk * CHUNK;
    float s1 = 0.f, s2 = 0.f;
    #pragma unroll
    for (int r = 0; r < 4; ++r) {
        float v = accf[r];
        int row = quad * 4 + r;                  // i_local
        x[(size_t)(ibase + row) * OUTD + w * 16 + m] = v;
        s1 += v; s2 += v * v;
    }
    // sum over the 16 rows: reduce across quads (lanes differing in bits 4..5)
    s1 += __shfl_xor(s1, 16); s1 += __shfl_xor(s1, 32);
    s2 += __shfl_xor(s2, 16); s2 += __shfl_xor(s2, 32);
    if (lane < 16) {
        psum  [bid * OUTD + w * 16 + lane] = s1;
        psumsq[bid * OUTD + w * 16 + lane] = s2;
    }
}

// Kernel 2: reduce per-block partials -> mean / invstd per output column
__global__ void k_stats(const float* __restrict__ psum, const float* __restrict__ psumsq,
                        float* __restrict__ mean, float* __restrict__ invstd) {
    int o = blockIdx.x;      // 64 blocks
    int t = threadIdx.x;     // 64 threads (1 wave)
    float s1 = 0.f, s2 = 0.f;
    for (int b = t; b < NBLK; b += 64) {
        s1 += psum[b * OUTD + o];
        s2 += psumsq[b * OUTD + o];
    }
    #pragma unroll
    for (int d = 1; d < 64; d <<= 1) {
        s1 += __shfl_xor(s1, d);
        s2 += __shfl_xor(s2, d);
    }
    if (t == 0) {
        const float inv_n = 1.0f / (float)(NFRAMES * NPED);
        float mu  = s1 * inv_n;
        float var = s2 * inv_n - mu * mu;        // biased (training-mode BN)
        mean[o]   = mu;
        invstd[o] = rsqrtf(var + EPSV);
    }
}

// Kernel 3: BN apply + ReLU
__global__ void k_apply(const float* __restrict__ x, const float* __restrict__ mean,
                        const float* __restrict__ invstd, const float* __restrict__ gamma,
                        const float* __restrict__ beta, float* __restrict__ out) {
    int g = blockIdx.x * 256 + threadIdx.x;
    int o = g & (OUTD - 1);
    float v = (x[g] - mean[o]) * invstd[o] * gamma[o] + beta[o];
    out[g] = v > 0.f ? v : 0.f;
}

extern "C" void kernel_launch(void* const* d_in, const int* in_sizes, int n_in,
                              void* d_out, int out_size, void* d_ws, size_t ws_size,
                              hipStream_t stream) {
    const float* hs    = (const float*)d_in[0];  // hidden_states [4096,64]
    const float* pos   = (const float*)d_in[1];  // all_pos [4096,2]
    const float* W     = (const float*)d_in[2];  // [4096,64]
    // d_in[3] = b: cancels exactly through BatchNorm -> unused
    const float* gamma = (const float*)d_in[4];
    const float* beta  = (const float*)d_in[5];
    // d_in[6] = seq_start_end: frames are uniform (i*128), hardcoded

    char* ws = (char*)d_ws;
    unsigned short* Wt = (unsigned short*)ws;                    // 512 KB
    float* x      = (float*)(ws + (512 << 10));                  // 1 MB
    float* psum   = (float*)(ws + (512 << 10) + (1 << 20));      // 64 KB
    float* psumsq = psum + NBLK * OUTD;                          // 64 KB
    float* mean   = psumsq + NBLK * OUTD;
    float* invstd = mean + OUTD;

    k_wt   <<<(OUTD * KDIM) / 256, 256, 0, stream>>>(W, Wt);
    k_fused<<<NBLK, 256, 0, stream>>>(hs, pos, Wt, x, psum, psumsq);
    k_stats<<<OUTD, 64, 0, stream>>>(psum, psumsq, mean, invstd);
    k_apply<<<(NFRAMES * NPED * OUTD) / 256, 256, 0, stream>>>(x, mean, invstd, gamma, beta,
                                                               (float*)d_out);
}

// Round 2
// 133.341 us; speedup vs baseline: 1.0056x; 1.0056x over previous
//
#include <hip/hip_runtime.h>
#include <hip/hip_bf16.h>
#include <math.h>

// Problem constants (fixed by reference)
#define NFRAMES 32
#define NPED    128
#define HDIM    64
#define KDIM    4096     // G*G*H
#define OUTD    64
#define EPSV    1e-5f
#define NBLK    256      // NFRAMES * (NPED/16)
#define KH      2048     // half-K per gy-pass (cells 0..31 / 32..63)
#define PSTR    2052     // 2048 + 4 f32 pad -> row bank shift 4, breaks conflicts

typedef __attribute__((ext_vector_type(8))) short  short8;
typedef __attribute__((ext_vector_type(4))) float  floatx4;
typedef __attribute__((ext_vector_type(4))) int    intx4;

static __device__ __forceinline__ unsigned short f2bf(float f) {
    union { float f; unsigned u; } v; v.f = f;
    unsigned r = v.u + 0x7fffu + ((v.u >> 16) & 1u);   // RNE (no NaNs here)
    return (unsigned short)(r >> 16);
}

// Kernel 0: Wt[o][k] = bf16(W[k][o]) via LDS-tiled transpose (coalesced both sides)
__global__ void k_wt(const float* __restrict__ W, unsigned short* __restrict__ Wt) {
    __shared__ float T[64 * 65];                 // +1 pad breaks bank conflicts
    const int t  = threadIdx.x;
    const int k0 = blockIdx.x * 64;
    #pragma unroll
    for (int it = 0; it < 16; ++it) {            // read 64k x 64o tile, coalesced
        int idx = it * 256 + t;
        int kl = idx >> 6, o = idx & 63;
        T[kl * 65 + o] = W[(size_t)(k0 + kl) * OUTD + o];
    }
    __syncthreads();
    #pragma unroll
    for (int it = 0; it < 8; ++it) {             // write transposed, 4B/lane contiguous
        int idx = it * 256 + t;
        int o = idx >> 5, kl = (idx & 31) * 2;
        unsigned v = (unsigned)f2bf(T[kl * 65 + o]) |
                     ((unsigned)f2bf(T[(kl + 1) * 65 + o]) << 16);
        *(unsigned*)(Wt + (size_t)o * KDIM + k0 + kl) = v;
    }
}

// Kernel 1: fused social-pool (f32 LDS + ds_add_f32 fire-and-forget atomics,
// two gy-half passes) + MFMA GEMM + BN partial sums.
// One block per (frame, 16-ped chunk): 256 blocks, 256 threads (4 waves).
__global__ __launch_bounds__(256, 1) void k_fused(
    const float* __restrict__ hs, const float* __restrict__ pos,
    const unsigned short* __restrict__ Wt,
    float* __restrict__ x, float* __restrict__ psumT, float* __restrict__ psumsqT)
{
    __shared__ float P32[16 * PSTR];             // 131328 B half-K f32 pool
    __shared__ float posL[NPED * 2];

    const int tid   = threadIdx.x;
    const int bid   = blockIdx.x;
    const int f     = bid >> 3;
    const int chunk = bid & 7;
    const int lane  = tid & 63;
    const int w     = tid >> 6;

    posL[tid] = pos[f * (NPED * 2) + tid];
    for (int idx = tid; idx < 16 * PSTR; idx += 256) P32[idx] = 0.f;

    const float* hsF = hs + f * (NPED * HDIM);
    const int m    = lane & 15;
    const int quad = lane >> 4;
    floatx4 acc[4];
    #pragma unroll
    for (int u = 0; u < 4; ++u) acc[u] = (floatx4){0.f, 0.f, 0.f, 0.f};
    const float* Prow = P32 + m * PSTR;
    const unsigned short* WtRow = Wt + (size_t)(w * 16 + m) * KDIM;

    __syncthreads();

    #pragma unroll
    for (int pass = 0; pass < 2; ++pass) {
        if (pass == 1) {
            __syncthreads();                     // pass-0 GEMM done reading P32
            for (int idx = tid; idx < 16 * PSTR; idx += 256) P32[idx] = 0.f;
            __syncthreads();
        }
        // ---- scatter: lane = j (per half), wave w owns rows w*4..w*4+3 ----
        #pragma unroll
        for (int half = 0; half < 2; ++half) {
            const int j0 = half * 64 + lane;
            const float xj = posL[j0 * 2], yj = posL[j0 * 2 + 1];
            #pragma unroll
            for (int r = 0; r < 4; ++r) {
                const int row = w * 4 + r;
                const int iF  = chunk * 16 + row;
                const float xi = posL[iF * 2], yi = posL[iF * 2 + 1];
                const float tlx = xi - 1.0f, tly = yi + 1.0f;
                bool valid = (xj > tlx) & (yj < tly) & (xj < xi + 1.0f) &
                             (yj > yi - 1.0f) & (j0 != iF);
                int gx = (int)floorf((xj - tlx) * 4.0f);   // == floor((xj-tlx)/NS*G)
                int gy = (int)floorf((tly - yj) * 4.0f);
                int c  = gx + 8 * gy;                      // 0..63 when valid
                unsigned long long msk = __ballot(valid && ((c >> 5) == pass));
                while (msk) {                              // wave-uniform scalar loop
                    int jb[4], cc[4]; float hv[4]; bool act[4];
                    #pragma unroll
                    for (int t = 0; t < 4; ++t) {          // batch 4: overlap load latency
                        act[t] = (msk != 0ULL);
                        jb[t]  = act[t] ? (__ffsll(msk) - 1) : 0;
                        msk   &= (msk - 1);
                        cc[t]  = __builtin_amdgcn_readlane(c, jb[t]);
                        hv[t]  = hsF[(half * 64 + jb[t]) * HDIM + lane];
                    }
                    #pragma unroll
                    for (int t = 0; t < 4; ++t)
                        if (act[t])
                            atomicAdd(&P32[row * PSTR + (cc[t] & 31) * 64 + lane], hv[t]);
                }
            }
        }
        __syncthreads();
        // ---- GEMM over this half-K: X += P[16, 2048] @ Wt[pass half]^T ----
        const unsigned short* wB = WtRow + pass * KH;
        for (int kk = 0; kk < KH; kk += 128) {
            #pragma unroll
            for (int u = 0; u < 4; ++u) {
                int k0 = kk + u * 32 + quad * 8;
                floatx4 p0 = *(const floatx4*)(Prow + k0);
                floatx4 p1 = *(const floatx4*)(Prow + k0 + 4);
                union { floatx4 fv; unsigned uv[4]; } U0, U1;
                U0.fv = p0; U1.fv = p1;
                // truncate f32->bf16, pack pairs: low short = hi16(even elem)
                intx4 ai = (intx4){
                    (int)__builtin_amdgcn_perm(U0.uv[1], U0.uv[0], 0x07060302u),
                    (int)__builtin_amdgcn_perm(U0.uv[3], U0.uv[2], 0x07060302u),
                    (int)__builtin_amdgcn_perm(U1.uv[1], U1.uv[0], 0x07060302u),
                    (int)__builtin_amdgcn_perm(U1.uv[3], U1.uv[2], 0x07060302u)};
                union { intx4 iv; short8 sv; } A; A.iv = ai;
                short8 bfrag = *(const short8*)(wB + k0);
                acc[u] = __builtin_amdgcn_mfma_f32_16x16x32_bf16(A.sv, bfrag, acc[u], 0, 0, 0);
            }
        }
    }

    // ---- epilogue: x write + BN partials (bias b cancels through BN) ----
    floatx4 accf = (acc[0] + acc[1]) + (acc[2] + acc[3]);
    const int ibase = f * NPED + chunk * 16;
    float s1 = 0.f, s2 = 0.f;
    #pragma unroll
    for (int r = 0; r < 4; ++r) {
        float v = accf[r];
        int row = quad * 4 + r;                  // D: row = quad*4+reg, col = lane&15
        x[(size_t)(ibase + row) * OUTD + w * 16 + m] = v;
        s1 += v; s2 += v * v;
    }
    s1 += __shfl_xor(s1, 16); s1 += __shfl_xor(s1, 32);
    s2 += __shfl_xor(s2, 16); s2 += __shfl_xor(s2, 32);
    if (lane < 16) {                             // transposed: k_stats reads coalesced
        psumT  [(w * 16 + lane) * NBLK + bid] = s1;
        psumsqT[(w * 16 + lane) * NBLK + bid] = s2;
    }
}

// Kernel 2: reduce per-block partials -> mean / invstd per output column
__global__ void k_stats(const float* __restrict__ psumT, const float* __restrict__ psumsqT,
                        float* __restrict__ mean, float* __restrict__ invstd) {
    int o = blockIdx.x;      // 64 blocks
    int t = threadIdx.x;     // 64 threads (1 wave)
    float s1 = 0.f, s2 = 0.f;
    #pragma unroll
    for (int i = 0; i < NBLK / 64; ++i) {
        s1 += psumT [o * NBLK + i * 64 + t];
        s2 += psumsqT[o * NBLK + i * 64 + t];
    }
    #pragma unroll
    for (int d = 1; d < 64; d <<= 1) {
        s1 += __shfl_xor(s1, d);
        s2 += __shfl_xor(s2, d);
    }
    if (t == 0) {
        const float inv_n = 1.0f / (float)(NFRAMES * NPED);
        float mu  = s1 * inv_n;
        float var = s2 * inv_n - mu * mu;        // biased (training-mode BN)
        mean[o]   = mu;
        invstd[o] = rsqrtf(var + EPSV);
    }
}

// Kernel 3: BN apply + ReLU (float4 vectorized)
__global__ void k_apply(const float* __restrict__ x, const float* __restrict__ mean,
                        const float* __restrict__ invstd, const float* __restrict__ gamma,
                        const float* __restrict__ beta, float* __restrict__ out) {
    int g = blockIdx.x * 256 + threadIdx.x;      // 65536 float4 groups
    int oq = g & 15;                             // float4-group within the 64 cols
    float4 xv = ((const float4*)x)[g];
    float4 mu = ((const float4*)mean)[oq];
    float4 is = ((const float4*)invstd)[oq];
    float4 ga = ((const float4*)gamma)[oq];
    float4 be = ((const float4*)beta)[oq];
    float4 r;
    r.x = (xv.x - mu.x) * is.x * ga.x + be.x;
    r.y = (xv.y - mu.y) * is.y * ga.y + be.y;
    r.z = (xv.z - mu.z) * is.z * ga.z + be.z;
    r.w = (xv.w - mu.w) * is.w * ga.w + be.w;
    r.x = r.x > 0.f ? r.x : 0.f;
    r.y = r.y > 0.f ? r.y : 0.f;
    r.z = r.z > 0.f ? r.z : 0.f;
    r.w = r.w > 0.f ? r.w : 0.f;
    ((float4*)out)[g] = r;
}

extern "C" void kernel_launch(void* const* d_in, const int* in_sizes, int n_in,
                              void* d_out, int out_size, void* d_ws, size_t ws_size,
                              hipStream_t stream) {
    const float* hs    = (const float*)d_in[0];  // hidden_states [4096,64]
    const float* pos   = (const float*)d_in[1];  // all_pos [4096,2]
    const float* W     = (const float*)d_in[2];  // [4096,64]
    // d_in[3] = b: cancels exactly through BatchNorm -> unused
    const float* gamma = (const float*)d_in[4];
    const float* beta  = (const float*)d_in[5];
    // d_in[6] = seq_start_end: frames are uniform (i*128), hardcoded

    char* ws = (char*)d_ws;
    unsigned short* Wt = (unsigned short*)ws;                    // 512 KB
    float* x       = (float*)(ws + (512 << 10));                 // 1 MB
    float* psumT   = (float*)(ws + (512 << 10) + (1 << 20));     // 64 KB
    float* psumsqT = psumT + NBLK * OUTD;                        // 64 KB
    float* mean    = psumsqT + NBLK * OUTD;
    float* invstd  = mean + OUTD;

    k_wt   <<<KDIM / 64, 256, 0, stream>>>(W, Wt);
    k_fused<<<NBLK, 256, 0, stream>>>(hs, pos, Wt, x, psumT, psumsqT);
    k_stats<<<OUTD, 64, 0, stream>>>(psumT, psumsqT, mean, invstd);
    k_apply<<<(NFRAMES * NPED * OUTD / 4) / 256, 256, 0, stream>>>(x, mean, invstd, gamma, beta,
                                                                   (float*)d_out);
}